// Round 1
// baseline (121.158 us; speedup 1.0000x reference)
//
#include <hip/hip_runtime.h>
#include <math.h>

#define BATCH 16
#define KVH 8
#define QM 8
#define NH 64
#define HD 128
#define CACHE 8192
#define WIN 4096
#define TOTAL (CACHE + 1)
#define PSTART (TOTAL - WIN)      // 4097: first unmasked position
#define TILE 64
#define KSTRIDE (KVH * HD)        // 1024 floats per cache row
#define LDSTR 132                 // LDS row stride (floats), 16B-aligned
#define REC_FLOATS (QM * (HD + 2))  // per (b,kvh,chunk) record: m[8], l[8], acc[8][128]

// ---------------------------------------------------------------------------
// Kernel 1: per-chunk partial attention (online softmax within the chunk).
// grid = (NC, KVH, BATCH), block = 256 threads (4 waves).
// Thread t: head h = t>>5 (0..7), lane-in-group lp = t&31.
// acc ownership: thread owns dims d = lp + 32*j, j=0..3 of head h.
// ---------------------------------------------------------------------------
template <int NC>
__global__ __launch_bounds__(256, 4)
void attn_partial(const float* __restrict__ Q,
                  const float* __restrict__ Knew,
                  const float* __restrict__ Vnew,
                  const float* __restrict__ Kc,
                  const float* __restrict__ Vc,
                  float* __restrict__ ws) {
    constexpr int CL = WIN / NC;      // positions per chunk (multiple of TILE)
    const int c   = blockIdx.x;
    const int kvh = blockIdx.y;
    const int b   = blockIdx.z;
    const int t   = threadIdx.x;

    __shared__ float q_s[QM][HD];
    __shared__ float kv_s[TILE][LDSTR];
    __shared__ float w_s[QM][TILE];

    // stage Q (pre-scaled by 1/sqrt(HD))
    {
        const float* qp = Q + ((size_t)b * NH + kvh * QM) * HD;
        for (int i = t; i < QM * HD; i += 256)
            q_s[i / HD][i % HD] = qp[i] * 0.08838834764831845f;
    }
    __syncthreads();

    const int h  = t >> 5;
    const int lp = t & 31;

    float acc0 = 0.f, acc1 = 0.f, acc2 = 0.f, acc3 = 0.f;
    float m_run = -INFINITY;   // replicated across the 32 lanes of each head group
    float l_run = 0.f;

    const size_t cache_base = (size_t)b * CACHE * KSTRIDE + (size_t)kvh * HD;
    const size_t new_base   = (size_t)b * KSTRIDE + (size_t)kvh * HD;
    const int p_base = PSTART + c * CL;

    for (int tb = 0; tb < CL; tb += TILE) {
        // ---- stage K tile (64 rows x 128 floats) ----
        for (int i = t; i < TILE * (HD / 4); i += 256) {
            int r = i >> 5;           // 32 float4 granules per row
            int g = i & 31;
            int p = p_base + tb + r;
            const float* src = (p < CACHE) ? (Kc + cache_base + (size_t)p * KSTRIDE)
                                           : (Knew + new_base);
            float4 v = *reinterpret_cast<const float4*>(src + g * 4);
            *reinterpret_cast<float4*>(&kv_s[r][g * 4]) = v;
        }
        __syncthreads();

        // ---- scores for (h, lp) and (h, lp+32) ----
        float s0 = 0.f, s1 = 0.f;
        {
            const float* qrow = q_s[h];
            const float* k0 = kv_s[lp];
            const float* k1 = kv_s[lp + 32];
            #pragma unroll
            for (int d = 0; d < HD; d += 4) {
                float4 qv  = *reinterpret_cast<const float4*>(qrow + d);
                float4 kv0 = *reinterpret_cast<const float4*>(k0 + d);
                float4 kv1 = *reinterpret_cast<const float4*>(k1 + d);
                s0 += qv.x * kv0.x + qv.y * kv0.y + qv.z * kv0.z + qv.w * kv0.w;
                s1 += qv.x * kv1.x + qv.y * kv1.y + qv.z * kv1.z + qv.w * kv1.w;
            }
        }

        // ---- online softmax update (32-lane butterfly per head group) ----
        float mt = fmaxf(s0, s1);
        #pragma unroll
        for (int off = 16; off; off >>= 1) mt = fmaxf(mt, __shfl_xor(mt, off));
        float m_new = fmaxf(m_run, mt);
        float e0 = __expf(s0 - m_new);
        float e1 = __expf(s1 - m_new);
        float rs = __expf(m_run - m_new);   // 0 on first tile (m_run = -inf)
        float lsum = e0 + e1;
        #pragma unroll
        for (int off = 16; off; off >>= 1) lsum += __shfl_xor(lsum, off);
        l_run = l_run * rs + lsum;
        m_run = m_new;
        acc0 *= rs; acc1 *= rs; acc2 *= rs; acc3 *= rs;
        w_s[h][lp]      = e0;
        w_s[h][lp + 32] = e1;
        __syncthreads();    // w_s visible; done reading K from kv_s

        // ---- stage V tile over kv_s ----
        for (int i = t; i < TILE * (HD / 4); i += 256) {
            int r = i >> 5;
            int g = i & 31;
            int p = p_base + tb + r;
            const float* src = (p < CACHE) ? (Vc + cache_base + (size_t)p * KSTRIDE)
                                           : (Vnew + new_base);
            float4 v = *reinterpret_cast<const float4*>(src + g * 4);
            *reinterpret_cast<float4*>(&kv_s[r][g * 4]) = v;
        }
        __syncthreads();

        // ---- PV accumulate ----
        #pragma unroll 4
        for (int p = 0; p < TILE; ++p) {
            float wv = w_s[h][p];
            acc0 += wv * kv_s[p][lp];
            acc1 += wv * kv_s[p][lp + 32];
            acc2 += wv * kv_s[p][lp + 64];
            acc3 += wv * kv_s[p][lp + 96];
        }
        __syncthreads();    // kv_s/w_s free for next tile
    }

    // ---- write partial record ----
    float* rec = ws + (size_t)((b * KVH + kvh) * NC + c) * REC_FLOATS;
    if (lp == 0) { rec[h] = m_run; rec[QM + h] = l_run; }
    float* accp = rec + 2 * QM + h * HD;
    accp[lp]      = acc0;
    accp[lp + 32] = acc1;
    accp[lp + 64] = acc2;
    accp[lp + 96] = acc3;
}

// ---------------------------------------------------------------------------
// Kernel 2: combine chunk partials + sink logit.
// grid = (KVH, BATCH), block = 256.
// ---------------------------------------------------------------------------
template <int NC>
__global__ __launch_bounds__(256)
void attn_combine(const float* __restrict__ ws,
                  const float* __restrict__ sinks,
                  float* __restrict__ out) {
    const int kvh = blockIdx.x;
    const int b   = blockIdx.y;
    const int t   = threadIdx.x;
    const int h   = t >> 5;
    const int lp  = t & 31;

    const float* base = ws + (size_t)((b * KVH + kvh) * NC) * REC_FLOATS;
    const float sk = sinks[kvh * QM + h];

    float m[NC], l[NC];
    float M = sk;
    #pragma unroll
    for (int c = 0; c < NC; ++c) {
        m[c] = base[(size_t)c * REC_FLOATS + h];
        l[c] = base[(size_t)c * REC_FLOATS + QM + h];
        M = fmaxf(M, m[c]);
    }
    float denom = __expf(sk - M);   // sink contributes to denominator only
    float wgt[NC];
    #pragma unroll
    for (int c = 0; c < NC; ++c) {
        wgt[c] = __expf(m[c] - M);
        denom += wgt[c] * l[c];
    }
    float inv = 1.f / denom;

    float o0 = 0.f, o1 = 0.f, o2 = 0.f, o3 = 0.f;
    #pragma unroll
    for (int c = 0; c < NC; ++c) {
        const float* accp = base + (size_t)c * REC_FLOATS + 2 * QM + h * HD;
        o0 += wgt[c] * accp[lp];
        o1 += wgt[c] * accp[lp + 32];
        o2 += wgt[c] * accp[lp + 64];
        o3 += wgt[c] * accp[lp + 96];
    }
    float* op = out + (size_t)b * NH * HD + (size_t)(kvh * QM + h) * HD;
    op[lp]      = o0 * inv;
    op[lp + 32] = o1 * inv;
    op[lp + 64] = o2 * inv;
    op[lp + 96] = o3 * inv;
}

// ---------------------------------------------------------------------------
template <int NC>
static void launch_nc(const float* Q, const float* K, const float* V,
                      const float* Kc, const float* Vc, const float* sinks,
                      float* out, float* ws, hipStream_t stream) {
    dim3 g1(NC, KVH, BATCH);
    attn_partial<NC><<<g1, 256, 0, stream>>>(Q, K, V, Kc, Vc, ws);
    dim3 g2(KVH, BATCH);
    attn_combine<NC><<<g2, 256, 0, stream>>>(ws, sinks, out);
}

extern "C" void kernel_launch(void* const* d_in, const int* in_sizes, int n_in,
                              void* d_out, int out_size, void* d_ws, size_t ws_size,
                              hipStream_t stream) {
    const float* Q     = (const float*)d_in[0];
    const float* K     = (const float*)d_in[1];
    const float* V     = (const float*)d_in[2];
    const float* Kc    = (const float*)d_in[3];
    const float* Vc    = (const float*)d_in[4];
    const float* sinks = (const float*)d_in[5];
    float* out = (float*)d_out;
    float* ws  = (float*)d_ws;

    auto need = [](int nc) {
        return (size_t)BATCH * KVH * nc * REC_FLOATS * sizeof(float);
    };
    if (ws_size >= need(8))      launch_nc<8>(Q, K, V, Kc, Vc, sinks, out, ws, stream);
    else if (ws_size >= need(4)) launch_nc<4>(Q, K, V, Kc, Vc, sinks, out, ws, stream);
    else if (ws_size >= need(2)) launch_nc<2>(Q, K, V, Kc, Vc, sinks, out, ws, stream);
    else                         launch_nc<1>(Q, K, V, Kc, Vc, sinks, out, ws, stream);
}